// Round 1
// 316.720 us; speedup vs baseline: 1.0490x; 1.0490x over previous
//
#include <hip/hip_runtime.h>
#include <hip/hip_bf16.h>
#include <cstdint>

// Problem sizes (fixed by reference setup_inputs)
#define B_SZ 8192
#define F_SZ 4096
#define D_SZ 1024
#define K_SZ 2048  // 2*D : A = [x^2 | x], W = [inv2 | -2*mu*inv2]

typedef __bf16 bf16x8 __attribute__((ext_vector_type(8)));
typedef float f32x4 __attribute__((ext_vector_type(4)));     // MFMA acc
typedef float fvec4 __attribute__((ext_vector_type(4)));
typedef unsigned short u16x4 __attribute__((ext_vector_type(4)));

// round-to-nearest-even fp32 -> bf16 bits
__device__ __forceinline__ unsigned short f2bf(float f) {
    union { float f; unsigned u; } c; c.f = f;
    unsigned r = c.u + 0x7fff + ((c.u >> 16) & 1);
    return (unsigned short)(r >> 16);
}

// async global->LDS, 16 B per lane; LDS dest = wave-uniform base + lane*16
__device__ __forceinline__ void async16(const void* g, void* l) {
    __builtin_amdgcn_global_load_lds(
        (__attribute__((address_space(1))) void*)g,
        (__attribute__((address_space(3))) void*)l, 16, 0, 0);
}

// ---------------------------------------------------------------------------
// prep: UNCHANGED from round-0 kernel (byte-identical numerics). Kept as-is so
// the gemm rewrite is the only variable this round; prep's true dur_us will
// surface in next round's top-5 now that gemm should drop under it.
// ---------------------------------------------------------------------------
__global__ __launch_bounds__(256) void prep(const float* __restrict__ x,
                                            const float* __restrict__ mu,
                                            const float* __restrict__ sd,
                                            unsigned short* __restrict__ A,
                                            unsigned short* __restrict__ W,
                                            float* __restrict__ nmm) {
    const int tid = threadIdx.x;
    if (blockIdx.x < 4096) {
        const size_t o0 = (size_t)blockIdx.x * 2048 + tid * 4;
        fvec4 v0 = *(const fvec4*)(x + o0);
        fvec4 v1 = *(const fvec4*)(x + o0 + 1024);
        #pragma unroll
        for (int h = 0; h < 2; ++h) {
            fvec4 v = h ? v1 : v0;
            size_t oo = o0 + h * 1024;
            size_t b = oo >> 10;
            int d = (int)(oo & 1023);
            u16x4 xx, xs;
            xx.x = f2bf(v.x * v.x); xx.y = f2bf(v.y * v.y);
            xx.z = f2bf(v.z * v.z); xx.w = f2bf(v.w * v.w);
            xs.x = f2bf(v.x); xs.y = f2bf(v.y);
            xs.z = f2bf(v.z); xs.w = f2bf(v.w);
            *(u16x4*)(A + b * K_SZ + d) = xx;
            *(u16x4*)(A + b * K_SZ + 1024 + d) = xs;
        }
    } else {
        const int f = blockIdx.x - 4096;
        const int d = tid * 4;
        size_t off = (size_t)f * D_SZ + d;
        fvec4 m = *(const fvec4*)(mu + off);
        fvec4 s = *(const fvec4*)(sd + off);
        float i0 = 1.0f / (s.x * s.x), i1 = 1.0f / (s.y * s.y);
        float i2 = 1.0f / (s.z * s.z), i3 = 1.0f / (s.w * s.w);
        u16x4 wi, wm;
        wi.x = f2bf(i0); wi.y = f2bf(i1); wi.z = f2bf(i2); wi.w = f2bf(i3);
        wm.x = f2bf(-2.0f * m.x * i0); wm.y = f2bf(-2.0f * m.y * i1);
        wm.z = f2bf(-2.0f * m.z * i2); wm.w = f2bf(-2.0f * m.w * i3);
        size_t wb = (size_t)f * K_SZ + d;
        *(u16x4*)(W + wb) = wi;
        *(u16x4*)(W + wb + 1024) = wm;
        float mm = m.x * m.x * i0 + m.y * m.y * i1 + m.z * m.z * i2 + m.w * m.w * i3;
        #pragma unroll
        for (int o = 32; o > 0; o >>= 1) mm += __shfl_down(mm, o, 64);
        __shared__ float red[4];
        if ((tid & 63) == 0) red[tid >> 6] = mm;
        __syncthreads();
        if (tid == 0) nmm[f] = -0.5f * (red[0] + red[1] + red[2] + red[3]);
    }
}

// ---------------------------------------------------------------------------
// GEMM: out[b,f] = -0.5 * (A @ W^T)[b,f] + nmm[f]
// 256x256 tile, BK=64, 512 threads = 8 waves (2M x 4N), per-wave 128x64 out.
// 8-phase counted-vmcnt schedule (T3+T4) + XOR LDS swizzle (T2) + setprio (T5).
//
// LDS: s{A,B}[2 dbuf][2 K-half][256 rows][32 cols] bf16 = 128 KiB total.
// Half-tile = one [dbuf][kk] region = 16 KiB = 2 global_load_lds issues.
//
// Swizzle: 16B-chunk c within a 64B row stored at c^(row&3); staging
// pre-swizzles the GLOBAL source col (LDS dest stays linear, rule #21),
// ds_read applies the same XOR. Gives 4 lanes per 16B bank-slot per
// 32-lane half-wave (derived conflict-free for ds_read_b128).
//
// Schedule per iteration (tiles T=2X in buf0 ph1-4, T+1 in buf1 ph5-8):
//   ph1: rd B.k0+A[0:4).k0 (buf0) | stage T+1.A.k0 | mfma        | bar
//   ph2: rd A[4:8).k0              | stage T+1.B.k0 | mfma | vm4 | bar
//   ph3: rd B.k1+A[0:4).k1         | stage T+1.A.k1 | mfma        | bar
//   ph4: rd A[4:8).k1              | stage T+1.B.k1 | mfma | vm4 | bar
//   ph5-8: same on buf1, staging T+2 into buf0 (regions retired ph1-4).
// vmcnt(4) at even-phase end = last 2 half-tiles stay in flight (never 0).
// WAR: every staged region's prior readers finished >=3 barriers earlier.
// RAW: each half-tile is vm4-covered 1+ barrier before its first ds_read.
// Last iteration peeled: no ph5-8 staging, vmcnt(0) at ph6.
// Accumulation order per output = ascending 32-wide K chunks (same as the
// previous 128x32 kernel) -> numerics identical.
// ---------------------------------------------------------------------------
__global__ __launch_bounds__(512, 2) void gemm_bt(const unsigned short* __restrict__ A,
                                                  const unsigned short* __restrict__ W,
                                                  const float* __restrict__ nmm,
                                                  float* __restrict__ out) {
    __shared__ __align__(16) unsigned short sA[2][2][256 * 32];
    __shared__ __align__(16) unsigned short sB[2][2][256 * 32];

    const int tid  = threadIdx.x;
    const int wave = tid >> 6;
    const int lane = tid & 63;
    const int r16  = lane & 15;
    const int quad = lane >> 4;
    const int wmB  = (wave >> 2) * 128;     // wave m-offset in 256 tile
    const int wnB  = (wave & 3) * 64;       // wave n-offset in 256 tile
    const int tileM = blockIdx.y * 256;
    const int tileN = blockIdx.x * 256;

    // staging coords: per gload issue, thread t covers row srow, 16B-chunk schunk
    const int srow   = tid >> 2;            // 0..127 (issue adds 0/128)
    const int schunk = tid & 3;

    const f32x4 vzero = {0.f, 0.f, 0.f, 0.f};
    f32x4 acc[8][4];
    #pragma unroll
    for (int i = 0; i < 8; ++i)
        #pragma unroll
        for (int j = 0; j < 4; ++j) acc[i][j] = vzero;

    bf16x8 af[4], bfr[4];

#define BARW() __builtin_amdgcn_s_barrier()
#define LGK()  asm volatile("s_waitcnt lgkmcnt(0)" ::: "memory")
#define VM4()  asm volatile("s_waitcnt vmcnt(4)" ::: "memory")
#define VM0()  asm volatile("s_waitcnt vmcnt(0)" ::: "memory")

// stage one half-tile (256 rows x 32 cols) of matrix G into S[DB][KK].
// 2 issues x 512 threads x 16 B. Global col pre-swizzled: chunk^(row&3).
#define STAGE(S, G, TB, DB, KK, KT)                                          \
    { _Pragma("unroll")                                                      \
      for (int is_ = 0; is_ < 2; ++is_) {                                    \
          int rr_ = is_ * 128 + srow;                                        \
          int gc_ = ((schunk ^ (rr_ & 3)) << 3);                             \
          async16(G + (size_t)((TB) + rr_) * K_SZ + (KT) * 64 + (KK) * 32 + gc_, \
                  &S[DB][KK][0] + is_ * 4096 + wave * 512);                  \
      } }

#define READ_A(I0, DB, KK)                                                   \
    { _Pragma("unroll")                                                      \
      for (int i_ = 0; i_ < 4; ++i_) {                                       \
          int row_ = wmB + ((I0) + i_) * 16 + r16;                           \
          af[i_] = *(const bf16x8*)(&sA[DB][KK][0] + row_ * 32 +             \
                                    (((quad ^ row_) & 3) << 3));             \
      } }

#define READ_B(DB, KK)                                                       \
    { _Pragma("unroll")                                                      \
      for (int j_ = 0; j_ < 4; ++j_) {                                       \
          int row_ = wnB + j_ * 16 + r16;                                    \
          bfr[j_] = *(const bf16x8*)(&sB[DB][KK][0] + row_ * 32 +            \
                                     (((quad ^ row_) & 3) << 3));            \
      } }

#define MFMA16(I0)                                                           \
    __builtin_amdgcn_s_setprio(1);                                          \
    { _Pragma("unroll")                                                      \
      for (int i_ = 0; i_ < 4; ++i_)                                         \
          _Pragma("unroll")                                                  \
          for (int j_ = 0; j_ < 4; ++j_)                                     \
              acc[(I0) + i_][j_] = __builtin_amdgcn_mfma_f32_16x16x32_bf16(  \
                  af[i_], bfr[j_], acc[(I0) + i_][j_], 0, 0, 0); }           \
    __builtin_amdgcn_s_setprio(0);

// One phase. RB: reload B frags. VM: -1 none, 4 vmcnt(4), 0 vmcnt(0).
#define PH(RB, I0, DB, KK, DOSTG, SBUF, G, TB, SDB, SKK, SKT, VM)            \
    { if (RB) READ_B(DB, KK)                                                 \
      READ_A(I0, DB, KK)                                                     \
      if (DOSTG) STAGE(SBUF, G, TB, SDB, SKK, SKT)                           \
      BARW(); LGK();                                                         \
      MFMA16(I0)                                                             \
      if ((VM) == 4) VM4(); else if ((VM) == 0) VM0();                       \
      BARW(); }

// Iteration: process tiles T (buf0) and T+1 (buf1); stage T+1 (ph1-4) and,
// if S58, T+2 (ph5-8). Epilogue (S58=0): vmcnt(0) at ph6 covers T+1.k1.
#define ITER(T, S58)                                                         \
    PH(1, 0, 0, 0, 1,      sA, A, tileM, 1, 0, (T) + 1, -1)                  \
    PH(0, 4, 0, 0, 1,      sB, W, tileN, 1, 0, (T) + 1, 4)                   \
    PH(1, 0, 0, 1, 1,      sA, A, tileM, 1, 1, (T) + 1, -1)                  \
    PH(0, 4, 0, 1, 1,      sB, W, tileN, 1, 1, (T) + 1, 4)                   \
    PH(1, 0, 1, 0, (S58),  sA, A, tileM, 0, 0, (T) + 2, -1)                  \
    PH(0, 4, 1, 0, (S58),  sB, W, tileN, 0, 0, (T) + 2, (S58) ? 4 : 0)       \
    PH(1, 0, 1, 1, (S58),  sA, A, tileM, 0, 1, (T) + 2, -1)                  \
    PH(0, 4, 1, 1, (S58),  sB, W, tileN, 0, 1, (T) + 2, -1)

    // prologue: stage tile0 fully into buf0; first 2 half-tiles guaranteed.
    STAGE(sA, A, tileM, 0, 0, 0)
    STAGE(sB, W, tileN, 0, 0, 0)
    STAGE(sA, A, tileM, 0, 1, 0)
    STAGE(sB, W, tileN, 0, 1, 0)
    VM4(); BARW();

    #pragma unroll 1
    for (int X = 0; X < 15; ++X) {
        const int T = 2 * X;
        ITER(T, 1)
    }
    {
        const int T = 30;
        ITER(T, 0)
    }

#undef PH
#undef ITER

    // epilogue: C/D layout col=lane&15 (N/W side), row=quad*4+reg (M/A side)
    int   fc[4];
    float cj[4];
    #pragma unroll
    for (int j = 0; j < 4; ++j) {
        fc[j] = tileN + wnB + j * 16 + r16;
        cj[j] = nmm[fc[j]];
    }
    #pragma unroll
    for (int i = 0; i < 8; ++i) {
        int mbase = tileM + wmB + i * 16 + quad * 4;
        #pragma unroll
        for (int r = 0; r < 4; ++r) {
            float* orow = out + (size_t)(mbase + r) * F_SZ;
            #pragma unroll
            for (int j = 0; j < 4; ++j)
                orow[fc[j]] = -0.5f * acc[i][j][r] + cj[j];
        }
    }
}

extern "C" void kernel_launch(void* const* d_in, const int* in_sizes, int n_in,
                              void* d_out, int out_size, void* d_ws, size_t ws_size,
                              hipStream_t stream) {
    const float* x  = (const float*)d_in[0];
    const float* mu = (const float*)d_in[1];
    const float* sd = (const float*)d_in[2];
    float* out = (float*)d_out;

    // workspace: A (8192x2048 bf16, 33.5 MB) | W (4096x2048 bf16, 16.8 MB) | nmm (16 KB)
    unsigned short* A = (unsigned short*)d_ws;
    unsigned short* W = A + (size_t)B_SZ * K_SZ;
    float* nmm = (float*)(W + (size_t)F_SZ * K_SZ);

    prep<<<8192, 256, 0, stream>>>(x, mu, sd, A, W, nmm);
    gemm_bt<<<dim3(F_SZ / 256, B_SZ / 256), 512, 0, stream>>>(A, W, nmm, out);
}

// Round 2
// 304.103 us; speedup vs baseline: 1.0926x; 1.0415x over previous
//
#include <hip/hip_runtime.h>
#include <hip/hip_bf16.h>
#include <cstdint>

// Problem sizes (fixed by reference setup_inputs)
#define B_SZ 8192
#define F_SZ 4096
#define D_SZ 1024
#define K_SZ 2048  // 2*D : A = [x^2 | x], W = [inv2 | -2*mu*inv2]

typedef __bf16 bf16x8 __attribute__((ext_vector_type(8)));
typedef float f32x4 __attribute__((ext_vector_type(4)));     // MFMA acc
typedef float fvec4 __attribute__((ext_vector_type(4)));
typedef unsigned short u16x4 __attribute__((ext_vector_type(4)));

// round-to-nearest-even fp32 -> bf16 bits
__device__ __forceinline__ unsigned short f2bf(float f) {
    union { float f; unsigned u; } c; c.f = f;
    unsigned r = c.u + 0x7fff + ((c.u >> 16) & 1);
    return (unsigned short)(r >> 16);
}

// async global->LDS, 16 B per lane; LDS dest = wave-uniform base + lane*16
__device__ __forceinline__ void async16(const void* g, void* l) {
    __builtin_amdgcn_global_load_lds(
        (__attribute__((address_space(1))) void*)g,
        (__attribute__((address_space(3))) void*)l, 16, 0, 0);
}

// ---------------------------------------------------------------------------
// prep: UNCHANGED (byte-identical numerics). total - gemm ~ 155 us is still
// unattributed; once gemm drops below it, prep shows up in rocprof top-5 and
// we get its true duration next round.
// ---------------------------------------------------------------------------
__global__ __launch_bounds__(256) void prep(const float* __restrict__ x,
                                            const float* __restrict__ mu,
                                            const float* __restrict__ sd,
                                            unsigned short* __restrict__ A,
                                            unsigned short* __restrict__ W,
                                            float* __restrict__ nmm) {
    const int tid = threadIdx.x;
    if (blockIdx.x < 4096) {
        const size_t o0 = (size_t)blockIdx.x * 2048 + tid * 4;
        fvec4 v0 = *(const fvec4*)(x + o0);
        fvec4 v1 = *(const fvec4*)(x + o0 + 1024);
        #pragma unroll
        for (int h = 0; h < 2; ++h) {
            fvec4 v = h ? v1 : v0;
            size_t oo = o0 + h * 1024;
            size_t b = oo >> 10;
            int d = (int)(oo & 1023);
            u16x4 xx, xs;
            xx.x = f2bf(v.x * v.x); xx.y = f2bf(v.y * v.y);
            xx.z = f2bf(v.z * v.z); xx.w = f2bf(v.w * v.w);
            xs.x = f2bf(v.x); xs.y = f2bf(v.y);
            xs.z = f2bf(v.z); xs.w = f2bf(v.w);
            *(u16x4*)(A + b * K_SZ + d) = xx;
            *(u16x4*)(A + b * K_SZ + 1024 + d) = xs;
        }
    } else {
        const int f = blockIdx.x - 4096;
        const int d = tid * 4;
        size_t off = (size_t)f * D_SZ + d;
        fvec4 m = *(const fvec4*)(mu + off);
        fvec4 s = *(const fvec4*)(sd + off);
        float i0 = 1.0f / (s.x * s.x), i1 = 1.0f / (s.y * s.y);
        float i2 = 1.0f / (s.z * s.z), i3 = 1.0f / (s.w * s.w);
        u16x4 wi, wm;
        wi.x = f2bf(i0); wi.y = f2bf(i1); wi.z = f2bf(i2); wi.w = f2bf(i3);
        wm.x = f2bf(-2.0f * m.x * i0); wm.y = f2bf(-2.0f * m.y * i1);
        wm.z = f2bf(-2.0f * m.z * i2); wm.w = f2bf(-2.0f * m.w * i3);
        size_t wb = (size_t)f * K_SZ + d;
        *(u16x4*)(W + wb) = wi;
        *(u16x4*)(W + wb + 1024) = wm;
        float mm = m.x * m.x * i0 + m.y * m.y * i1 + m.z * m.z * i2 + m.w * m.w * i3;
        #pragma unroll
        for (int o = 32; o > 0; o >>= 1) mm += __shfl_down(mm, o, 64);
        __shared__ float red[4];
        if ((tid & 63) == 0) red[tid >> 6] = mm;
        __syncthreads();
        if (tid == 0) nmm[f] = -0.5f * (red[0] + red[1] + red[2] + red[3]);
    }
}

// ---------------------------------------------------------------------------
// GEMM: out[b,f] = -0.5 * (A @ W^T)[b,f] + nmm[f]
// 256x256 tile, BK=64, 512 threads = 8 waves (2M x 4N), per-wave 128x64 out.
// 8-phase counted-vmcnt schedule (T3+T4) + XOR LDS swizzle (T2) + setprio (T5).
//
// LDS: s{A,B}[2 dbuf][2 K-half][256 rows][32 cols] bf16 = 128 KiB total.
// Half-tile = one [dbuf][kk] region = 16 KiB = 2 global_load_lds issues.
//
// SWIZZLE (round-2 fix): bank-space slot of a 16B chunk = (row&1)*64 + c*16
// bytes (64B rows = half the 128B bank space -> only row bit0 is natural).
// Old XOR (row&3) left rows r and r+4 on identical banks (2-way, 1.26e7
// conflicts measured). New involution c ^= (row>>1)&3 injects row bits 1:2 so
// 8 consecutive rows cover all 8 distinct 16B slots -> conflict-free b128.
// Staging pre-swizzles the GLOBAL source col (LDS dest linear, rule #21);
// ds_read applies the same XOR.
//
// VMCNT LEDGER (round-2 fix: ph8 was missing its drain -> cross-wave race on
// buf0.kk0; benign by timing luck only). vmcnt(4) at EVERY even phase end,
// before the trailing barrier (drain-own-loads -> barrier -> others read):
//   entering ph1: 4 outstanding (prev ph7-8 = buf0.kk1), buf0.kk0 landed  -> ph1 safe
//   ph2 end: 8 -> drain prev ph7-8 (buf0.kk1)                            -> ph3 safe
//   ph4 end: 8 -> drain ph1-2 (buf1.kk0)                                 -> ph5 safe
//   ph6 end: 8 -> drain ph3-4 (buf1.kk1)                                 -> ph7 safe
//   ph8 end: 8 -> drain ph5-6 (next buf0.kk0)                            -> next ph1 safe
// Never drains to 0 in the main loop; >=2 half-tiles always in flight.
// Last iteration peeled: no ph5-8 staging, vmcnt(0) at ph6.
// Accumulation order per output = ascending 32-wide K chunks (numerics
// identical to all previous rounds).
// ---------------------------------------------------------------------------
__global__ __launch_bounds__(512, 2) void gemm_bt(const unsigned short* __restrict__ A,
                                                  const unsigned short* __restrict__ W,
                                                  const float* __restrict__ nmm,
                                                  float* __restrict__ out) {
    __shared__ __align__(16) unsigned short sA[2][2][256 * 32];
    __shared__ __align__(16) unsigned short sB[2][2][256 * 32];

    const int tid  = threadIdx.x;
    const int wave = tid >> 6;
    const int lane = tid & 63;
    const int r16  = lane & 15;
    const int quad = lane >> 4;
    const int wmB  = (wave >> 2) * 128;     // wave m-offset in 256 tile
    const int wnB  = (wave & 3) * 64;       // wave n-offset in 256 tile
    const int tileM = blockIdx.y * 256;
    const int tileN = blockIdx.x * 256;

    // staging coords: per gload issue, thread t covers row srow, 16B-chunk schunk
    const int srow   = tid >> 2;            // 0..127 (issue adds 0/128)
    const int schunk = tid & 3;

    const f32x4 vzero = {0.f, 0.f, 0.f, 0.f};
    f32x4 acc[8][4];
    #pragma unroll
    for (int i = 0; i < 8; ++i)
        #pragma unroll
        for (int j = 0; j < 4; ++j) acc[i][j] = vzero;

    bf16x8 af[4], bfr[4];

#define BARW() __builtin_amdgcn_s_barrier()
#define LGK()  asm volatile("s_waitcnt lgkmcnt(0)" ::: "memory")
#define VM4()  asm volatile("s_waitcnt vmcnt(4)" ::: "memory")
#define VM0()  asm volatile("s_waitcnt vmcnt(0)" ::: "memory")

// stage one half-tile (256 rows x 32 cols) of matrix G into S[DB][KK].
// 2 issues x 512 threads x 16 B. Global col pre-swizzled: chunk ^ ((row>>1)&3).
#define STAGE(S, G, TB, DB, KK, KT)                                          \
    { _Pragma("unroll")                                                      \
      for (int is_ = 0; is_ < 2; ++is_) {                                    \
          int rr_ = is_ * 128 + srow;                                        \
          int gc_ = ((schunk ^ ((rr_ >> 1) & 3)) << 3);                      \
          async16(G + (size_t)((TB) + rr_) * K_SZ + (KT) * 64 + (KK) * 32 + gc_, \
                  &S[DB][KK][0] + is_ * 4096 + wave * 512);                  \
      } }

#define READ_A(I0, DB, KK)                                                   \
    { _Pragma("unroll")                                                      \
      for (int i_ = 0; i_ < 4; ++i_) {                                       \
          int row_ = wmB + ((I0) + i_) * 16 + r16;                           \
          af[i_] = *(const bf16x8*)(&sA[DB][KK][0] + row_ * 32 +             \
                                    (((quad ^ (row_ >> 1)) & 3) << 3));      \
      } }

#define READ_B(DB, KK)                                                       \
    { _Pragma("unroll")                                                      \
      for (int j_ = 0; j_ < 4; ++j_) {                                       \
          int row_ = wnB + j_ * 16 + r16;                                    \
          bfr[j_] = *(const bf16x8*)(&sB[DB][KK][0] + row_ * 32 +            \
                                     (((quad ^ (row_ >> 1)) & 3) << 3));     \
      } }

#define MFMA16(I0)                                                           \
    __builtin_amdgcn_s_setprio(1);                                          \
    { _Pragma("unroll")                                                      \
      for (int i_ = 0; i_ < 4; ++i_)                                         \
          _Pragma("unroll")                                                  \
          for (int j_ = 0; j_ < 4; ++j_)                                     \
              acc[(I0) + i_][j_] = __builtin_amdgcn_mfma_f32_16x16x32_bf16(  \
                  af[i_], bfr[j_], acc[(I0) + i_][j_], 0, 0, 0); }           \
    __builtin_amdgcn_s_setprio(0);

// One phase. RB: reload B frags. VM: -1 none, 4 vmcnt(4), 0 vmcnt(0).
#define PH(RB, I0, DB, KK, DOSTG, SBUF, G, TB, SDB, SKK, SKT, VM)            \
    { if (RB) READ_B(DB, KK)                                                 \
      READ_A(I0, DB, KK)                                                     \
      if (DOSTG) STAGE(SBUF, G, TB, SDB, SKK, SKT)                           \
      BARW(); LGK();                                                         \
      MFMA16(I0)                                                             \
      if ((VM) == 4) VM4(); else if ((VM) == 0) VM0();                       \
      BARW(); }

// Iteration: process tiles T (buf0) and T+1 (buf1); stage T+1 (ph1-4) and,
// if S58, T+2 (ph5-8). Epilogue (S58=0): vmcnt(0) at ph6 covers T+1.k1.
#define ITER(T, S58)                                                         \
    PH(1, 0, 0, 0, 1,      sA, A, tileM, 1, 0, (T) + 1, -1)                  \
    PH(0, 4, 0, 0, 1,      sB, W, tileN, 1, 0, (T) + 1, 4)                   \
    PH(1, 0, 0, 1, 1,      sA, A, tileM, 1, 1, (T) + 1, -1)                  \
    PH(0, 4, 0, 1, 1,      sB, W, tileN, 1, 1, (T) + 1, 4)                   \
    PH(1, 0, 1, 0, (S58),  sA, A, tileM, 0, 0, (T) + 2, -1)                  \
    PH(0, 4, 1, 0, (S58),  sB, W, tileN, 0, 0, (T) + 2, (S58) ? 4 : 0)       \
    PH(1, 0, 1, 1, (S58),  sA, A, tileM, 0, 1, (T) + 2, -1)                  \
    PH(0, 4, 1, 1, (S58),  sB, W, tileN, 0, 1, (T) + 2, (S58) ? 4 : -1)

    // prologue: stage tile0 fully into buf0 (order A.k0,B.k0,A.k1,B.k1);
    // vmcnt(4) lands the first two half-tiles (kk0) before ph1 reads them.
    STAGE(sA, A, tileM, 0, 0, 0)
    STAGE(sB, W, tileN, 0, 0, 0)
    STAGE(sA, A, tileM, 0, 1, 0)
    STAGE(sB, W, tileN, 0, 1, 0)
    VM4(); BARW();

    #pragma unroll 1
    for (int X = 0; X < 15; ++X) {
        const int T = 2 * X;
        ITER(T, 1)
    }
    {
        const int T = 30;
        ITER(T, 0)
    }

#undef PH
#undef ITER

    // epilogue: C/D layout col=lane&15 (N/W side), row=quad*4+reg (M/A side)
    int   fc[4];
    float cj[4];
    #pragma unroll
    for (int j = 0; j < 4; ++j) {
        fc[j] = tileN + wnB + j * 16 + r16;
        cj[j] = nmm[fc[j]];
    }
    #pragma unroll
    for (int i = 0; i < 8; ++i) {
        int mbase = tileM + wmB + i * 16 + quad * 4;
        #pragma unroll
        for (int r = 0; r < 4; ++r) {
            float* orow = out + (size_t)(mbase + r) * F_SZ;
            #pragma unroll
            for (int j = 0; j < 4; ++j)
                orow[fc[j]] = -0.5f * acc[i][j][r] + cj[j];
        }
    }
}

extern "C" void kernel_launch(void* const* d_in, const int* in_sizes, int n_in,
                              void* d_out, int out_size, void* d_ws, size_t ws_size,
                              hipStream_t stream) {
    const float* x  = (const float*)d_in[0];
    const float* mu = (const float*)d_in[1];
    const float* sd = (const float*)d_in[2];
    float* out = (float*)d_out;

    // workspace: A (8192x2048 bf16, 33.5 MB) | W (4096x2048 bf16, 16.8 MB) | nmm (16 KB)
    unsigned short* A = (unsigned short*)d_ws;
    unsigned short* W = A + (size_t)B_SZ * K_SZ;
    float* nmm = (float*)(W + (size_t)F_SZ * K_SZ);

    prep<<<8192, 256, 0, stream>>>(x, mu, sd, A, W, nmm);
    gemm_bt<<<dim3(F_SZ / 256, B_SZ / 256), 512, 0, stream>>>(A, W, nmm, out);
}

// Round 3
// 300.136 us; speedup vs baseline: 1.1070x; 1.0132x over previous
//
#include <hip/hip_runtime.h>
#include <hip/hip_bf16.h>
#include <cstdint>

// Problem sizes (fixed by reference setup_inputs)
#define B_SZ 8192
#define F_SZ 4096
#define D_SZ 1024
#define K_SZ 2048  // 2*D : A = [x^2 | x], W = [inv2 | -2*mu*inv2]

typedef __bf16 bf16x8 __attribute__((ext_vector_type(8)));
typedef float f32x4 __attribute__((ext_vector_type(4)));     // MFMA acc
typedef float fvec4 __attribute__((ext_vector_type(4)));
typedef unsigned short u16x4 __attribute__((ext_vector_type(4)));

// round-to-nearest-even fp32 -> bf16 bits
__device__ __forceinline__ unsigned short f2bf(float f) {
    union { float f; unsigned u; } c; c.f = f;
    unsigned r = c.u + 0x7fff + ((c.u >> 16) & 1);
    return (unsigned short)(r >> 16);
}

// async global->LDS, 16 B per lane; LDS dest = wave-uniform base + lane*16
__device__ __forceinline__ void async16(const void* g, void* l) {
    __builtin_amdgcn_global_load_lds(
        (__attribute__((address_space(1))) void*)g,
        (__attribute__((address_space(3))) void*)l, 16, 0, 0);
}

// ---------------------------------------------------------------------------
// prep: UNCHANGED (byte-identical numerics). Doesn't show in rocprof top-5 so
// prep < 145 us; the (total - gemm) gap likely includes harness restore
// dispatches. Revisit only after gemm converges.
// ---------------------------------------------------------------------------
__global__ __launch_bounds__(256) void prep(const float* __restrict__ x,
                                            const float* __restrict__ mu,
                                            const float* __restrict__ sd,
                                            unsigned short* __restrict__ A,
                                            unsigned short* __restrict__ W,
                                            float* __restrict__ nmm) {
    const int tid = threadIdx.x;
    if (blockIdx.x < 4096) {
        const size_t o0 = (size_t)blockIdx.x * 2048 + tid * 4;
        fvec4 v0 = *(const fvec4*)(x + o0);
        fvec4 v1 = *(const fvec4*)(x + o0 + 1024);
        #pragma unroll
        for (int h = 0; h < 2; ++h) {
            fvec4 v = h ? v1 : v0;
            size_t oo = o0 + h * 1024;
            size_t b = oo >> 10;
            int d = (int)(oo & 1023);
            u16x4 xx, xs;
            xx.x = f2bf(v.x * v.x); xx.y = f2bf(v.y * v.y);
            xx.z = f2bf(v.z * v.z); xx.w = f2bf(v.w * v.w);
            xs.x = f2bf(v.x); xs.y = f2bf(v.y);
            xs.z = f2bf(v.z); xs.w = f2bf(v.w);
            *(u16x4*)(A + b * K_SZ + d) = xx;
            *(u16x4*)(A + b * K_SZ + 1024 + d) = xs;
        }
    } else {
        const int f = blockIdx.x - 4096;
        const int d = tid * 4;
        size_t off = (size_t)f * D_SZ + d;
        fvec4 m = *(const fvec4*)(mu + off);
        fvec4 s = *(const fvec4*)(sd + off);
        float i0 = 1.0f / (s.x * s.x), i1 = 1.0f / (s.y * s.y);
        float i2 = 1.0f / (s.z * s.z), i3 = 1.0f / (s.w * s.w);
        u16x4 wi, wm;
        wi.x = f2bf(i0); wi.y = f2bf(i1); wi.z = f2bf(i2); wi.w = f2bf(i3);
        wm.x = f2bf(-2.0f * m.x * i0); wm.y = f2bf(-2.0f * m.y * i1);
        wm.z = f2bf(-2.0f * m.z * i2); wm.w = f2bf(-2.0f * m.w * i3);
        size_t wb = (size_t)f * K_SZ + d;
        *(u16x4*)(W + wb) = wi;
        *(u16x4*)(W + wb + 1024) = wm;
        float mm = m.x * m.x * i0 + m.y * m.y * i1 + m.z * m.z * i2 + m.w * m.w * i3;
        #pragma unroll
        for (int o = 32; o > 0; o >>= 1) mm += __shfl_down(mm, o, 64);
        __shared__ float red[4];
        if ((tid & 63) == 0) red[tid >> 6] = mm;
        __syncthreads();
        if (tid == 0) nmm[f] = -0.5f * (red[0] + red[1] + red[2] + red[3]);
    }
}

// ---------------------------------------------------------------------------
// GEMM: out[b,f] = -0.5 * (A @ W^T)[b,f] + nmm[f]
// 256x256 tile, BK=64, 512 threads = 8 waves (2M x 4N), per-wave 128x64 out.
//
// ROUND-3 STRUCTURE: single trailing barrier per phase (mid-phase barrier and
// forced lgkmcnt(0) removed -- compiler emits fine-grained lgkmcnt so the
// first MFMA starts once af[0]/bfr[0] land, overlapping the remaining
// ds_reads). Drains relaxed to vmcnt(4)@ph4 + vmcnt(6)@ph8 only (m201's
// discipline), never 0 in the main loop.
//
// LDS: s{A,B}[2 dbuf][2 K-half][256 rows][32 cols] bf16 = 128 KiB.
// Swizzle (verified: bank conflicts == 0 in rocprof): 16B chunk c stored at
// c ^ ((row>>1)&3); staging pre-swizzles the GLOBAL source col (LDS dest
// linear, rule #21), ds_read applies the same involution.
//
// VMCNT LEDGER (phase k stages 2 loads; drain-own -> trailing barrier ->
// cross-wave read; distances to READ, which is at phase START):
//   steady ph4 end: outstanding = {prev6,7,8}+{ph1..4} = 14 -> vmcnt(4)
//     guarantees through ph2:  ph5 reads prev5(ok@prev-ph8),prev6(ok)
//                              ph7 reads prev7,prev8(ok); next-ph1 reads ph1,ph2(ok)
//   steady ph8 end: outstanding = {ph3,4}+{ph5..8} = 12 -> vmcnt(6)
//     guarantees through ph5:  next-ph3 reads ph3,ph4(ok); next-ph5 reads ph5(ok),
//                              ph6(drained next-ph4, ok)
//   iter0 (prologue leaves kk1's 4 loads outstanding): ph4: 4+8=12 -> vmcnt(4)
//     drains prol-kk1+ph1+ph2 (ok); ph8: 4+8=12 -> vmcnt(6) drains ph3,4,5 (ok).
//   Min issue->guarantee slack ~2.5 phases (~1300 cyc) > ~900 cyc HBM latency.
// WAR: region read in ph k is re-stage-ISSUED >= 3 trailing barriers later; the
// reads were consumed (lgkm-enforced) before their own phase's barrier. Safe.
// Last iteration peeled: no ph5-8 staging; vmcnt(0)@ph6 drains ph3,ph4 for
// ph7/ph8 reads.
// Accumulation order per output = ascending 32-wide K chunks (numerics
// identical to all previous rounds).
// ---------------------------------------------------------------------------
__global__ __launch_bounds__(512, 2) void gemm_bt(const unsigned short* __restrict__ A,
                                                  const unsigned short* __restrict__ W,
                                                  const float* __restrict__ nmm,
                                                  float* __restrict__ out) {
    __shared__ __align__(16) unsigned short sA[2][2][256 * 32];
    __shared__ __align__(16) unsigned short sB[2][2][256 * 32];

    const int tid  = threadIdx.x;
    const int wave = tid >> 6;
    const int lane = tid & 63;
    const int r16  = lane & 15;
    const int quad = lane >> 4;
    const int wmB  = (wave >> 2) * 128;     // wave m-offset in 256 tile
    const int wnB  = (wave & 3) * 64;       // wave n-offset in 256 tile
    const int tileM = blockIdx.y * 256;
    const int tileN = blockIdx.x * 256;

    // staging coords: per gload issue, thread t covers row srow, 16B-chunk schunk
    const int srow   = tid >> 2;            // 0..127 (issue adds 0/128)
    const int schunk = tid & 3;

    const f32x4 vzero = {0.f, 0.f, 0.f, 0.f};
    f32x4 acc[8][4];
    #pragma unroll
    for (int i = 0; i < 8; ++i)
        #pragma unroll
        for (int j = 0; j < 4; ++j) acc[i][j] = vzero;

    bf16x8 af[4], bfr[4];

#define BARW() __builtin_amdgcn_s_barrier()
#define VM4()  asm volatile("s_waitcnt vmcnt(4)" ::: "memory")
#define VM6()  asm volatile("s_waitcnt vmcnt(6)" ::: "memory")
#define VM0()  asm volatile("s_waitcnt vmcnt(0)" ::: "memory")

// stage one half-tile (256 rows x 32 cols) of matrix G into S[DB][KK].
// 2 issues x 512 threads x 16 B. Global col pre-swizzled: chunk ^ ((row>>1)&3).
#define STAGE(S, G, TB, DB, KK, KT)                                          \
    { _Pragma("unroll")                                                      \
      for (int is_ = 0; is_ < 2; ++is_) {                                    \
          int rr_ = is_ * 128 + srow;                                        \
          int gc_ = ((schunk ^ ((rr_ >> 1) & 3)) << 3);                      \
          async16(G + (size_t)((TB) + rr_) * K_SZ + (KT) * 64 + (KK) * 32 + gc_, \
                  &S[DB][KK][0] + is_ * 4096 + wave * 512);                  \
      } }

#define READ_A(I0, DB, KK)                                                   \
    { _Pragma("unroll")                                                      \
      for (int i_ = 0; i_ < 4; ++i_) {                                       \
          int row_ = wmB + ((I0) + i_) * 16 + r16;                           \
          af[i_] = *(const bf16x8*)(&sA[DB][KK][0] + row_ * 32 +             \
                                    (((quad ^ (row_ >> 1)) & 3) << 3));      \
      } }

#define READ_B(DB, KK)                                                       \
    { _Pragma("unroll")                                                      \
      for (int j_ = 0; j_ < 4; ++j_) {                                       \
          int row_ = wnB + j_ * 16 + r16;                                    \
          bfr[j_] = *(const bf16x8*)(&sB[DB][KK][0] + row_ * 32 +            \
                                     (((quad ^ (row_ >> 1)) & 3) << 3));     \
      } }

#define MFMA16(I0)                                                           \
    __builtin_amdgcn_s_setprio(1);                                          \
    { _Pragma("unroll")                                                      \
      for (int i_ = 0; i_ < 4; ++i_)                                         \
          _Pragma("unroll")                                                  \
          for (int j_ = 0; j_ < 4; ++j_)                                     \
              acc[(I0) + i_][j_] = __builtin_amdgcn_mfma_f32_16x16x32_bf16(  \
                  af[i_], bfr[j_], acc[(I0) + i_][j_], 0, 0, 0); }           \
    __builtin_amdgcn_s_setprio(0);

// One phase: {reads, stage-issue, MFMA, [drain], trailing barrier}.
// No mid barrier, no forced lgkmcnt(0): compiler fine-grains lgkm waits so
// MFMA overlaps the tail of the ds_reads. VM: -1 none, 4/6/0 = vmcnt(N).
#define PH(RB, I0, DB, KK, DOSTG, SBUF, G, TB, SDB, SKK, SKT, VM)            \
    { if (RB) READ_B(DB, KK)                                                 \
      READ_A(I0, DB, KK)                                                     \
      if (DOSTG) STAGE(SBUF, G, TB, SDB, SKK, SKT)                           \
      MFMA16(I0)                                                             \
      if ((VM) == 4) VM4(); else if ((VM) == 6) VM6(); else if ((VM) == 0) VM0(); \
      BARW(); }

// Iteration: process tiles T (buf0, ph1-4) and T+1 (buf1, ph5-8); stage T+1
// during ph1-4 and, if S58, T+2 during ph5-8. Drains per the ledger above.
#define ITER(T, S58)                                                         \
    PH(1, 0, 0, 0, 1,      sA, A, tileM, 1, 0, (T) + 1, -1)                  \
    PH(0, 4, 0, 0, 1,      sB, W, tileN, 1, 0, (T) + 1, -1)                  \
    PH(1, 0, 0, 1, 1,      sA, A, tileM, 1, 1, (T) + 1, -1)                  \
    PH(0, 4, 0, 1, 1,      sB, W, tileN, 1, 1, (T) + 1, 4)                   \
    PH(1, 0, 1, 0, (S58),  sA, A, tileM, 0, 0, (T) + 2, -1)                  \
    PH(0, 4, 1, 0, (S58),  sB, W, tileN, 0, 0, (T) + 2, (S58) ? -1 : 0)      \
    PH(1, 0, 1, 1, (S58),  sA, A, tileM, 0, 1, (T) + 2, -1)                  \
    PH(0, 4, 1, 1, (S58),  sB, W, tileN, 0, 1, (T) + 2, (S58) ? 6 : -1)

    // prologue: stage tile0 fully into buf0 (order A.k0,B.k0,A.k1,B.k1);
    // vmcnt(4) lands the kk0 half-tiles before ph1 reads them; kk1's 4 loads
    // stay outstanding (accounted in the iter-0 ledger).
    STAGE(sA, A, tileM, 0, 0, 0)
    STAGE(sB, W, tileN, 0, 0, 0)
    STAGE(sA, A, tileM, 0, 1, 0)
    STAGE(sB, W, tileN, 0, 1, 0)
    VM4(); BARW();

    #pragma unroll 1
    for (int X = 0; X < 15; ++X) {
        const int T = 2 * X;
        ITER(T, 1)
    }
    {
        const int T = 30;
        ITER(T, 0)
    }

#undef PH
#undef ITER

    // epilogue: C/D layout col=lane&15 (N/W side), row=quad*4+reg (M/A side)
    int   fc[4];
    float cj[4];
    #pragma unroll
    for (int j = 0; j < 4; ++j) {
        fc[j] = tileN + wnB + j * 16 + r16;
        cj[j] = nmm[fc[j]];
    }
    #pragma unroll
    for (int i = 0; i < 8; ++i) {
        int mbase = tileM + wmB + i * 16 + quad * 4;
        #pragma unroll
        for (int r = 0; r < 4; ++r) {
            float* orow = out + (size_t)(mbase + r) * F_SZ;
            #pragma unroll
            for (int j = 0; j < 4; ++j)
                orow[fc[j]] = -0.5f * acc[i][j][r] + cj[j];
        }
    }
}

extern "C" void kernel_launch(void* const* d_in, const int* in_sizes, int n_in,
                              void* d_out, int out_size, void* d_ws, size_t ws_size,
                              hipStream_t stream) {
    const float* x  = (const float*)d_in[0];
    const float* mu = (const float*)d_in[1];
    const float* sd = (const float*)d_in[2];
    float* out = (float*)d_out;

    // workspace: A (8192x2048 bf16, 33.5 MB) | W (4096x2048 bf16, 16.8 MB) | nmm (16 KB)
    unsigned short* A = (unsigned short*)d_ws;
    unsigned short* W = A + (size_t)B_SZ * K_SZ;
    float* nmm = (float*)(W + (size_t)F_SZ * K_SZ);

    prep<<<8192, 256, 0, stream>>>(x, mu, sd, A, W, nmm);
    gemm_bt<<<dim3(F_SZ / 256, B_SZ / 256), 512, 0, stream>>>(A, W, nmm, out);
}